// Round 4
// baseline (296.678 us; speedup 1.0000x reference)
//
#include <hip/hip_runtime.h>

#define EPS 1e-5f

typedef short short8 __attribute__((ext_vector_type(8)));
typedef float floatx4 __attribute__((ext_vector_type(4)));
typedef unsigned short ushort8 __attribute__((ext_vector_type(8)));

__device__ __forceinline__ unsigned short f2bf(float f) {
  unsigned int u = __float_as_uint(f);
  u = (u + 0x7FFFu + ((u >> 16) & 1u)) >> 16;
  return (unsigned short)u;
}
__device__ __forceinline__ float bf2f(unsigned short h) {
  return __uint_as_float(((unsigned int)h) << 16);
}

// ---------------------------------------------------------------------------
// Kernel 1: qkv[b][o][h] = BN(qkv_w @ x)  via bf16 MFMA 16x16x32.
// M=512(o), N=32768(n=b*64+h), K=256. Block: 64x64 tile, 256 thr (4 waves 2x2),
// BK=64. A=W (k-contig), staged bf16 [64][72]; B=x (n-contig), staged bf16
// [k][66] (odd-dword stride -> conflict-free u16 frag reads).
// ---------------------------------------------------------------------------
__global__ __launch_bounds__(256) void k_qkv_gemm(const float* __restrict__ x,
                                                  const float* __restrict__ W,
                                                  const float* __restrict__ bnq,
                                                  float* __restrict__ qkv) {
  __shared__ unsigned short A_lds[64 * 72];  // [m][k], stride 72 (144B rows, 16B-mult)
  __shared__ unsigned short B_lds[64 * 66];  // [k][n], stride 66 (odd dwords)
  const int tid = threadIdx.x;
  const int lane = tid & 63;
  const int wid = tid >> 6;
  const int wm = (wid >> 1) * 32, wn = (wid & 1) * 32;
  const int n0 = blockIdx.x * 64;  // n0 = b*64
  const int o0 = blockIdx.y * 64;
  const int l15 = lane & 15, kg = lane >> 4;

  floatx4 acc[2][2] = {};

  const int am = tid >> 2, akq = (tid & 3) * 16;   // A staging: row m, 16 k's
  const int bk = tid >> 2, bnq4 = (tid & 3) * 16;  // B staging: row k, 16 n's

  for (int ko = 0; ko < 256; ko += 64) {
    __syncthreads();
    // stage A: W[o0+am][ko+akq .. +15] -> bf16
    {
      unsigned short tmp[16];
#pragma unroll
      for (int u = 0; u < 4; ++u) {
        const float4 w4 =
            *reinterpret_cast<const float4*>(&W[(size_t)(o0 + am) * 256 + ko + akq + u * 4]);
        tmp[u * 4 + 0] = f2bf(w4.x);
        tmp[u * 4 + 1] = f2bf(w4.y);
        tmp[u * 4 + 2] = f2bf(w4.z);
        tmp[u * 4 + 3] = f2bf(w4.w);
      }
      *reinterpret_cast<ushort8*>(&A_lds[am * 72 + akq]) = *reinterpret_cast<ushort8*>(&tmp[0]);
      *reinterpret_cast<ushort8*>(&A_lds[am * 72 + akq + 8]) =
          *reinterpret_cast<ushort8*>(&tmp[8]);
    }
    // stage B: x[ko+bk][n0+bnq4 .. +15] -> bf16 (ushort2 writes: 4B-aligned)
    {
#pragma unroll
      for (int u = 0; u < 4; ++u) {
        const float4 x4 =
            *reinterpret_cast<const float4*>(&x[(size_t)(ko + bk) * 32768 + n0 + bnq4 + u * 4]);
        unsigned int p0 = (unsigned int)f2bf(x4.x) | ((unsigned int)f2bf(x4.y) << 16);
        unsigned int p1 = (unsigned int)f2bf(x4.z) | ((unsigned int)f2bf(x4.w) << 16);
        *reinterpret_cast<unsigned int*>(&B_lds[bk * 66 + bnq4 + u * 4]) = p0;
        *reinterpret_cast<unsigned int*>(&B_lds[bk * 66 + bnq4 + u * 4 + 2]) = p1;
      }
    }
    __syncthreads();
    // MFMA inner: kk = 0,32 within this BK=64
#pragma unroll
    for (int kk = 0; kk < 64; kk += 32) {
      short8 afr[2], bfr[2];
#pragma unroll
      for (int fm = 0; fm < 2; ++fm) {
        const int mrow = wm + fm * 16 + l15;
        afr[fm] = *reinterpret_cast<const short8*>(&A_lds[mrow * 72 + kk + kg * 8]);
      }
#pragma unroll
      for (int fn = 0; fn < 2; ++fn) {
        const int ncol = wn + fn * 16 + l15;
        short8 bv;
#pragma unroll
        for (int e = 0; e < 8; ++e)
          bv[e] = (short)B_lds[(kk + kg * 8 + e) * 66 + ncol];
        bfr[fn] = bv;
      }
#pragma unroll
      for (int fm = 0; fm < 2; ++fm)
#pragma unroll
        for (int fn = 0; fn < 2; ++fn)
          acc[fm][fn] =
              __builtin_amdgcn_mfma_f32_16x16x32_bf16(afr[fm], bfr[fn], acc[fm][fn], 0, 0, 0);
    }
  }

  // epilogue: C/D map col=lane&15 (n), row=(lane>>4)*4+reg (o). BN + store.
  const int b = blockIdx.x;
#pragma unroll
  for (int fm = 0; fm < 2; ++fm) {
    float sc[4], sh[4];
#pragma unroll
    for (int reg = 0; reg < 4; ++reg) {
      const int o = o0 + wm + fm * 16 + kg * 4 + reg;
      sc[reg] = bnq[o] / sqrtf(bnq[1536 + o] + EPS);
      sh[reg] = bnq[512 + o] - bnq[1024 + o] * sc[reg];
    }
#pragma unroll
    for (int fn = 0; fn < 2; ++fn) {
      const int h = wn + fn * 16 + l15;
#pragma unroll
      for (int reg = 0; reg < 4; ++reg) {
        const int o = o0 + wm + fm * 16 + kg * 4 + reg;
        qkv[((size_t)b * 512 + o) * 64 + h] = fmaf(acc[fm][fn][reg], sc[reg], sh[reg]);
      }
    }
  }
}

// ---------------------------------------------------------------------------
// Kernel 2: per (b,g) attention. 256 threads per block, one block per (b,g).
// LDS: qkv fp32 [64][65], rel bf16 [64][130] (odd-dword rows), S fp32 [64][68].
// Total 50.9 KB -> 3 blocks/CU.
// ---------------------------------------------------------------------------
__global__ __launch_bounds__(256) void k_attn(const float* __restrict__ qkv,
                                              const float* __restrict__ rel,
                                              const float* __restrict__ bns,
                                              const float* __restrict__ bno,
                                              float* __restrict__ out) {
  __shared__ float qkv_s[64 * 65];          // [cc][h], stride 65
  __shared__ unsigned short rel_bs[64 * 130];  // [cc][t] bf16, stride 130
  __shared__ float S_s[64 * 68];            // scores (stride 68), reused as out-tile
  __shared__ float rowsum_s[64];
  const int tid = threadIdx.x;
  const int bg = blockIdx.x;
  const int b = bg >> 3, g = bg & 7;

  // --- stage qkv block (fp32) + relative table (bf16) ---
  const float* src = qkv + ((size_t)b * 512 + (size_t)g * 64) * 64;
  for (int idx = tid; idx < 4096; idx += 256)
    qkv_s[(idx >> 6) * 65 + (idx & 63)] = src[idx];
  for (int idx = tid; idx < 8192; idx += 256) {
    const int r = idx >> 7, c = idx & 127;
    if (c < 127) rel_bs[r * 130 + c] = f2bf(rel[r * 127 + c]);
  }
  __syncthreads();

  // --- step 2: scores.  j fixed per thread; i = (tid>>6) + 4r ---
  {
    const int j = tid & 63;
    float kcol[16];
#pragma unroll
    for (int c = 0; c < 16; ++c) kcol[c] = qkv_s[(16 + c) * 65 + j];
    const float scA = bns[g] / sqrtf(bns[72 + g] + EPS);
    const float scB = bns[8 + g] / sqrtf(bns[72 + 8 + g] + EPS);
    const float scC = bns[16 + g] / sqrtf(bns[72 + 16 + g] + EPS);
    const float sh = (bns[24 + g] - bns[48 + g] * scA) +
                     (bns[24 + 8 + g] - bns[48 + 8 + g] * scB) +
                     (bns[24 + 16 + g] - bns[48 + 16 + g] * scC);
#pragma unroll 4
    for (int r = 0; r < 16; ++r) {
      const int i = (tid >> 6) + 4 * r;
      const int base = i - j + 63;  // in [0,126]
      float qk = 0.f, qr = 0.f, kr = 0.f;
#pragma unroll
      for (int c = 0; c < 16; ++c) {
        const float qv = qkv_s[c * 65 + i];
        qk = fmaf(qv, kcol[c], qk);
        qr = fmaf(qv, bf2f(rel_bs[c * 130 + base]), qr);
        kr = fmaf(kcol[c], bf2f(rel_bs[(16 + c) * 130 + 126 - base]), kr);
      }
      S_s[i * 68 + j] = fmaf(scA, qk, fmaf(scB, qr, fmaf(scC, kr, sh)));
    }
  }
  __syncthreads();

  // --- step 3: softmax over j (4 threads per row, float4, shuffle reduce) ---
  {
    const int i = tid >> 2, sub = tid & 3;
    float* row = S_s + i * 68 + sub * 16;
    float4 v0 = reinterpret_cast<float4*>(row)[0];
    float4 v1 = reinterpret_cast<float4*>(row)[1];
    float4 v2 = reinterpret_cast<float4*>(row)[2];
    float4 v3 = reinterpret_cast<float4*>(row)[3];
    float m = fmaxf(fmaxf(fmaxf(v0.x, v0.y), fmaxf(v0.z, v0.w)),
                    fmaxf(fmaxf(v1.x, v1.y), fmaxf(v1.z, v1.w)));
    m = fmaxf(m, fmaxf(fmaxf(fmaxf(v2.x, v2.y), fmaxf(v2.z, v2.w)),
                       fmaxf(fmaxf(v3.x, v3.y), fmaxf(v3.z, v3.w))));
    m = fmaxf(m, __shfl_xor(m, 1));
    m = fmaxf(m, __shfl_xor(m, 2));
    float sum = 0.f;
    float4 e0, e1, e2, e3;
    e0.x = __expf(v0.x - m); e0.y = __expf(v0.y - m); e0.z = __expf(v0.z - m); e0.w = __expf(v0.w - m);
    e1.x = __expf(v1.x - m); e1.y = __expf(v1.y - m); e1.z = __expf(v1.z - m); e1.w = __expf(v1.w - m);
    e2.x = __expf(v2.x - m); e2.y = __expf(v2.y - m); e2.z = __expf(v2.z - m); e2.w = __expf(v2.w - m);
    e3.x = __expf(v3.x - m); e3.y = __expf(v3.y - m); e3.z = __expf(v3.z - m); e3.w = __expf(v3.w - m);
    sum = e0.x + e0.y + e0.z + e0.w + e1.x + e1.y + e1.z + e1.w +
          e2.x + e2.y + e2.z + e2.w + e3.x + e3.y + e3.z + e3.w;
    reinterpret_cast<float4*>(row)[0] = e0;
    reinterpret_cast<float4*>(row)[1] = e1;
    reinterpret_cast<float4*>(row)[2] = e2;
    reinterpret_cast<float4*>(row)[3] = e3;
    sum += __shfl_xor(sum, 1);
    sum += __shfl_xor(sum, 2);
    if (sub == 0) rowsum_s[i] = sum;
  }
  __syncthreads();

  // --- step 4: sv/sve + output BN.  c fixed per thread; i = (tid>>5) + 8r ---
  const int c = tid & 31;
  float vrow[64];
#pragma unroll
  for (int jj = 0; jj < 64; ++jj) vrow[jj] = qkv_s[(32 + c) * 65 + jj];
  const unsigned short* relc = rel_bs + (32 + c) * 130;
  const int ch = ((g << 5) + c) * 2;
  const float sc0 = bno[ch] / sqrtf(bno[1536 + ch] + EPS);
  const float sh0 = bno[512 + ch] - bno[1024 + ch] * sc0;
  const float sc1 = bno[ch + 1] / sqrtf(bno[1536 + ch + 1] + EPS);
  const float sh1 = bno[512 + ch + 1] - bno[1024 + ch + 1] * sc1;
  float outv[8];
#pragma unroll
  for (int r = 0; r < 8; ++r) {
    const int i = (tid >> 5) + 8 * r;
    const float* prow = S_s + i * 68;
    const int rbase = i + 63;
    float sv = 0.f, sve = 0.f;
#pragma unroll
    for (int jj4 = 0; jj4 < 16; ++jj4) {
      const float4 p4 = *reinterpret_cast<const float4*>(prow + jj4 * 4);
      const float pe[4] = {p4.x, p4.y, p4.z, p4.w};
#pragma unroll
      for (int e = 0; e < 4; ++e) {
        const int jj = jj4 * 4 + e;
        sv = fmaf(pe[e], vrow[jj], sv);
        sve = fmaf(pe[e], bf2f(relc[rbase - jj]), sve);
      }
    }
    const float inv = 1.0f / rowsum_s[i];
    outv[r] = fmaf(sc0, sv * inv, sh0) + fmaf(sc1, sve * inv, sh1);
  }
  __syncthreads();  // everyone done reading S_s as P
#pragma unroll
  for (int r = 0; r < 8; ++r) {
    const int i = (tid >> 5) + 8 * r;
    S_s[c * 68 + i] = outv[r];  // out-tile [c][i], stride 68
  }
  __syncthreads();
  const size_t outbase = (size_t)b * 64;
  for (int idx = tid; idx < 2048; idx += 256) {
    const int cc = idx >> 6, ii = idx & 63;
    out[(size_t)((g << 5) + cc) * 32768 + outbase + ii] = S_s[cc * 68 + ii];
  }
}

extern "C" void kernel_launch(void* const* d_in, const int* in_sizes, int n_in,
                              void* d_out, int out_size, void* d_ws, size_t ws_size,
                              hipStream_t stream) {
  const float* x = (const float*)d_in[0];         // (1,256,16,32,64)
  const float* qkv_w = (const float*)d_in[1];     // (512,256)
  const float* relative = (const float*)d_in[2];  // (64,127)
  const float* bn_qkv = (const float*)d_in[3];    // (4,512)
  const float* bn_sim = (const float*)d_in[4];    // (4,24)
  const float* bn_out = (const float*)d_in[5];    // (4,512)
  float* out = (float*)d_out;                     // (256, 512, 64) as [op][b][h]
  float* qkv = (float*)d_ws;                      // 512*512*64 floats = 64 MB

  k_qkv_gemm<<<dim3(512, 8), 256, 0, stream>>>(x, qkv_w, bn_qkv, qkv);
  k_attn<<<4096, 256, 0, stream>>>(qkv, relative, bn_sim, bn_out, out);
}